// Round 14
// baseline (213.467 us; speedup 1.0000x reference)
//
#include <hip/hip_runtime.h>
#include <cmath>

#define B_SZ 512
#define D_SZ 128
#define K_SZ 4096
#define NDATA 500000
#define TEMP 0.07f
#define MOM 0.5f
#define EPSN 1e-12f
#define SPLIT 8
#define WSB_OFF (1 << 20)  // fp8 shadow bank offset in d_ws (bytes)

typedef float f32x4 __attribute__((ext_vector_type(4)));
typedef float f32x2 __attribute__((ext_vector_type(2)));

// ---------------- kernel A: normalize s,t + pos logits ----------------
__global__ void knorm(const float* __restrict__ s_in, const float* __restrict__ t_in,
                      float* __restrict__ s_n, float* __restrict__ t_n,
                      float* __restrict__ pos) {
    int b = blockIdx.x;
    int l = threadIdx.x;  // 64 lanes, 2 floats each
    float2 sv = ((const float2*)(s_in + b * D_SZ))[l];
    float2 tv = ((const float2*)(t_in + b * D_SZ))[l];
    float ss = sv.x * sv.x + sv.y * sv.y;
    float tt = tv.x * tv.x + tv.y * tv.y;
    for (int m = 1; m < 64; m <<= 1) {
        ss += __shfl_xor(ss, m, 64);
        tt += __shfl_xor(tt, m, 64);
    }
    float sinv = 1.0f / fmaxf(sqrtf(ss), EPSN);
    float tinv = 1.0f / fmaxf(sqrtf(tt), EPSN);
    float2 sn = {sv.x * sinv, sv.y * sinv};
    float2 tn = {tv.x * tinv, tv.y * tinv};
    ((float2*)(s_n + b * D_SZ))[l] = sn;
    ((float2*)(t_n + b * D_SZ))[l] = tn;
    float d = sn.x * tn.x + sn.y * tn.y;
    for (int m = 1; m < 64; m <<= 1) d += __shfl_xor(d, m, 64);
    if (l == 0) pos[b] = d * (1.0f / TEMP);
}

// ---------------- pure copy: bank -> out+1 (plain loads, NT stores) ----------------
// out4[j] = { src[4j-1], src[4j], src[4j+1], src[4j+2] }
__global__ __launch_bounds__(256) void kcopy_pure(const float* __restrict__ src,
                                                  float* __restrict__ out /* d_out */) {
    const long long total = (long long)NDATA * D_SZ;  // 64,000,000
    const long long NV = total / 4;                   // 16,000,000
    long long t = blockIdx.x * 256LL + threadIdx.x;
    const long long nthr = gridDim.x * 256LL;
    const int lane = threadIdx.x & 63;
    const f32x4* src4 = (const f32x4*)src;
    f32x4* out4 = (f32x4*)out;
    for (long long j = t; j < NV; j += nthr) {
        f32x4 v = src4[j];  // plain cached load -> bank stays L3-resident
        float pw = __shfl_up(v.w, 1, 64);
        if (lane == 0 && j > 0) pw = src[4 * j - 1];  // cache-hit neighbor
        if (j > 0) {
            f32x4 w;
            w.x = pw; w.y = v.x; w.z = v.y; w.w = v.z;
            __builtin_nontemporal_store(w, out4 + j);  // NT: don't displace bank
        } else {
            out[1] = v.x; out[2] = v.y; out[3] = v.z;
            out[total] = src[total - 1];
        }
    }
}

// ---------------- emit: bank (L3-warm) -> fp8 shadow ----------------
__global__ __launch_bounds__(256) void kemit(const float* __restrict__ src,
                                             unsigned int* __restrict__ wsb) {
    const long long NV = (long long)NDATA * D_SZ / 4;  // 16,000,000
    long long t = blockIdx.x * 256LL + threadIdx.x;
    const long long nthr = gridDim.x * 256LL;
    const f32x4* src4 = (const f32x4*)src;
    for (long long j = t; j < NV; j += nthr) {
        f32x4 v = src4[j];  // mostly L3-hit right after kcopy_pure
        int w8 = __builtin_amdgcn_cvt_pk_fp8_f32(v.x, v.y, 0, false);
        w8 = __builtin_amdgcn_cvt_pk_fp8_f32(v.z, v.w, w8, true);
        wsb[j] = (unsigned int)w8;  // regular store -> L3-resident for gather
    }
}

// ---------------- fp8 dot helper: 16 elements vs s-chunk ----------------
__device__ __forceinline__ float dot16_fp8(uint4 h, f32x4 s0, f32x4 s1, f32x4 s2, f32x4 s3) {
    float d = 0.0f;
    f32x2 a, c;
    a = __builtin_amdgcn_cvt_pk_f32_fp8((int)h.x, false);
    c = __builtin_amdgcn_cvt_pk_f32_fp8((int)h.x, true);
    d += a.x * s0.x + a.y * s0.y + c.x * s0.z + c.y * s0.w;
    a = __builtin_amdgcn_cvt_pk_f32_fp8((int)h.y, false);
    c = __builtin_amdgcn_cvt_pk_f32_fp8((int)h.y, true);
    d += a.x * s1.x + a.y * s1.y + c.x * s1.z + c.y * s1.w;
    a = __builtin_amdgcn_cvt_pk_f32_fp8((int)h.z, false);
    c = __builtin_amdgcn_cvt_pk_f32_fp8((int)h.z, true);
    d += a.x * s2.x + a.y * s2.y + c.x * s2.z + c.y * s2.w;
    a = __builtin_amdgcn_cvt_pk_f32_fp8((int)h.w, false);
    c = __builtin_amdgcn_cvt_pk_f32_fp8((int)h.w, true);
    d += a.x * s3.x + a.y * s3.y + c.x * s3.z + c.y * s3.w;
    return d;
}

// ---------------- gather from fp8 shadow: 8 lanes/row, 8 rows in flight ----------------
__global__ __launch_bounds__(256) void kneg_fp8(const unsigned int* __restrict__ wsb,
                                                const int* __restrict__ negidx,
                                                const float* __restrict__ s_n,
                                                float2* __restrict__ partials) {
    const int split = blockIdx.x;  // 0..SPLIT-1
    const int b = blockIdx.y;
    const int tid = threadIdx.x;
    const int oct = tid >> 3;  // 32 octets of 8 lanes
    const int o = tid & 7;
    const f32x4* sn4 = (const f32x4*)(s_n + b * D_SZ + o * 16);
    f32x4 s0 = sn4[0], s1 = sn4[1], s2 = sn4[2], s3 = sn4[3];
    float m = -INFINITY, ssum = 0.0f;
    const int KB = K_SZ / SPLIT;             // 512 rows per block
    const int base = b * K_SZ + split * KB;
    for (int it = 0; it < KB / 256; ++it) {  // 2 iters; octet does 8 rows/iter
        int k = it * 256 + oct * 8;
        int4 ia = *(const int4*)(negidx + base + k);
        int4 ib = *(const int4*)(negidx + base + k + 4);
        uint4 h0 = ((const uint4*)(wsb + (long long)ia.x * 32))[o];
        uint4 h1 = ((const uint4*)(wsb + (long long)ia.y * 32))[o];
        uint4 h2 = ((const uint4*)(wsb + (long long)ia.z * 32))[o];
        uint4 h3 = ((const uint4*)(wsb + (long long)ia.w * 32))[o];
        uint4 h4 = ((const uint4*)(wsb + (long long)ib.x * 32))[o];
        uint4 h5 = ((const uint4*)(wsb + (long long)ib.y * 32))[o];
        uint4 h6 = ((const uint4*)(wsb + (long long)ib.z * 32))[o];
        uint4 h7 = ((const uint4*)(wsb + (long long)ib.w * 32))[o];
        float d0 = dot16_fp8(h0, s0, s1, s2, s3);
        float d1 = dot16_fp8(h1, s0, s1, s2, s3);
        float d2 = dot16_fp8(h2, s0, s1, s2, s3);
        float d3 = dot16_fp8(h3, s0, s1, s2, s3);
        float d4 = dot16_fp8(h4, s0, s1, s2, s3);
        float d5 = dot16_fp8(h5, s0, s1, s2, s3);
        float d6 = dot16_fp8(h6, s0, s1, s2, s3);
        float d7 = dot16_fp8(h7, s0, s1, s2, s3);
        for (int s = 1; s < 8; s <<= 1) {
            d0 += __shfl_xor(d0, s, 64);
            d1 += __shfl_xor(d1, s, 64);
            d2 += __shfl_xor(d2, s, 64);
            d3 += __shfl_xor(d3, s, 64);
            d4 += __shfl_xor(d4, s, 64);
            d5 += __shfl_xor(d5, s, 64);
            d6 += __shfl_xor(d6, s, 64);
            d7 += __shfl_xor(d7, s, 64);
        }
        d0 *= (1.0f / TEMP); d1 *= (1.0f / TEMP); d2 *= (1.0f / TEMP); d3 *= (1.0f / TEMP);
        d4 *= (1.0f / TEMP); d5 *= (1.0f / TEMP); d6 *= (1.0f / TEMP); d7 *= (1.0f / TEMP);
        float mx = fmaxf(fmaxf(fmaxf(d0, d1), fmaxf(d2, d3)),
                         fmaxf(fmaxf(d4, d5), fmaxf(d6, d7)));
        float mn = fmaxf(m, mx);
        ssum = ssum * __expf(m - mn) + __expf(d0 - mn) + __expf(d1 - mn) +
               __expf(d2 - mn) + __expf(d3 - mn) + __expf(d4 - mn) +
               __expf(d5 - mn) + __expf(d6 - mn) + __expf(d7 - mn);
        m = mn;
    }
    __shared__ float2 gp[32];
    if (o == 0) gp[oct] = make_float2(m, ssum);
    __syncthreads();
    if (tid == 0) {
        float M = gp[0].x, S = gp[0].y;
        for (int g = 1; g < 32; ++g) {
            float mg = gp[g].x, sg = gp[g].y;
            float mn = fmaxf(M, mg);
            S = S * __expf(M - mn) + sg * __expf(mg - mn);
            M = mn;
        }
        partials[b * SPLIT + split] = make_float2(M, S);
    }
}

// ---------------- momentum scatter-update (last-wins) ----------------
__global__ void kupdate(const int* __restrict__ indices, const float* __restrict__ bank,
                        const float* __restrict__ t_n, float* __restrict__ outBank /* d_out+1 */) {
    int j = blockIdx.x;
    int l = threadIdx.x;  // 64
    int idx = indices[j];
    for (int j2 = j + 1; j2 < B_SZ; ++j2)
        if (indices[j2] == idx) return;  // last occurrence wins
    float2 bv = ((const float2*)(bank + (long long)idx * D_SZ))[l];
    float2 tv = ((const float2*)(t_n + j * D_SZ))[l];
    float2 u = {MOM * bv.x + (1.0f - MOM) * tv.x, MOM * bv.y + (1.0f - MOM) * tv.y};
    float ss = u.x * u.x + u.y * u.y;
    for (int m = 1; m < 64; m <<= 1) ss += __shfl_xor(ss, m, 64);
    float inv = 1.0f / fmaxf(sqrtf(ss), EPSN);
    float* dst = outBank + (long long)idx * D_SZ + l * 2;
    dst[0] = u.x * inv;
    dst[1] = u.y * inv;
}

// ---------------- combine partials -> loss ----------------
__global__ void kfinal(const float2* __restrict__ partials, const float* __restrict__ pos,
                       float* __restrict__ out) {
    __shared__ float red[B_SZ];
    int t = threadIdx.x;  // 512
    float M = -INFINITY, S = 0.0f;
    for (int p = 0; p < SPLIT; ++p) {
        float2 ms = partials[t * SPLIT + p];
        float mn = fmaxf(M, ms.x);
        S = S * __expf(M - mn) + ms.y * __expf(ms.x - mn);
        M = mn;
    }
    float pl = pos[t];
    float mn = fmaxf(M, pl);
    S = S * __expf(M - mn) + __expf(pl - mn);
    M = mn;
    red[t] = M + logf(S) - pl;
    __syncthreads();
    for (int o = 256; o > 0; o >>= 1) {
        if (t < o) red[t] += red[t + o];
        __syncthreads();
    }
    if (t == 0) out[0] = red[0] * (1.0f / (float)B_SZ);
}

extern "C" void kernel_launch(void* const* d_in, const int* in_sizes, int n_in,
                              void* d_out, int out_size, void* d_ws, size_t ws_size,
                              hipStream_t stream) {
    const float* student = (const float*)d_in[0];
    const float* teacher = (const float*)d_in[1];
    const float* bank    = (const float*)d_in[2];
    const int*   indices = (const int*)d_in[3];
    const int*   negidx  = (const int*)d_in[4];
    float* out = (float*)d_out;

    // workspace: small arrays in first 1 MB, fp8 shadow bank after (61 MB)
    float* s_n      = (float*)d_ws;              // 65536 f
    float* t_n      = s_n + B_SZ * D_SZ;         // 65536 f
    float* pos      = t_n + B_SZ * D_SZ;         // 512 f
    float2* partials = (float2*)(pos + B_SZ);    // 512*SPLIT float2
    unsigned int* wsb = (unsigned int*)((char*)d_ws + WSB_OFF);

    knorm<<<B_SZ, 64, 0, stream>>>(student, teacher, s_n, t_n, pos);
    kcopy_pure<<<4096, 256, 0, stream>>>(bank, out);
    kemit<<<4096, 256, 0, stream>>>(bank, wsb);
    dim3 g(SPLIT, B_SZ);
    kneg_fp8<<<g, 256, 0, stream>>>(wsb, negidx, s_n, partials);
    kupdate<<<B_SZ, 64, 0, stream>>>(indices, bank, t_n, out + 1);
    kfinal<<<1, B_SZ, 0, stream>>>(partials, pos, out);
}

// Round 15
// 179.481 us; speedup vs baseline: 1.1894x; 1.1894x over previous
//
#include <hip/hip_runtime.h>
#include <cmath>

#define B_SZ 512
#define D_SZ 128
#define K_SZ 4096
#define NDATA 500000
#define TEMP 0.07f
#define MOM 0.5f
#define EPSN 1e-12f
#define SPLIT 8
#define WSB_OFF (1 << 20)  // fp8 shadow bank offset in d_ws (bytes)

typedef float f32x4 __attribute__((ext_vector_type(4)));
typedef float f32x2 __attribute__((ext_vector_type(2)));

// ---------------- kernel A: normalize s,t + pos logits ----------------
__global__ void knorm(const float* __restrict__ s_in, const float* __restrict__ t_in,
                      float* __restrict__ s_n, float* __restrict__ t_n,
                      float* __restrict__ pos) {
    int b = blockIdx.x;
    int l = threadIdx.x;  // 64 lanes, 2 floats each
    float2 sv = ((const float2*)(s_in + b * D_SZ))[l];
    float2 tv = ((const float2*)(t_in + b * D_SZ))[l];
    float ss = sv.x * sv.x + sv.y * sv.y;
    float tt = tv.x * tv.x + tv.y * tv.y;
    for (int m = 1; m < 64; m <<= 1) {
        ss += __shfl_xor(ss, m, 64);
        tt += __shfl_xor(tt, m, 64);
    }
    float sinv = 1.0f / fmaxf(sqrtf(ss), EPSN);
    float tinv = 1.0f / fmaxf(sqrtf(tt), EPSN);
    float2 sn = {sv.x * sinv, sv.y * sinv};
    float2 tn = {tv.x * tinv, tv.y * tinv};
    ((float2*)(s_n + b * D_SZ))[l] = sn;
    ((float2*)(t_n + b * D_SZ))[l] = tn;
    float d = sn.x * tn.x + sn.y * tn.y;
    for (int m = 1; m < 64; m <<= 1) d += __shfl_xor(d, m, 64);
    if (l == 0) pos[b] = d * (1.0f / TEMP);
}

// ---------------- copy+emit: plain loads, PLAIN stores (no NT anywhere) ----------------
// out[1+i] = bank[i]; wsb[j] = fp8(bank[4j..4j+3])
__global__ __launch_bounds__(256) void kcopy_emit(const float* __restrict__ src,
                                                  float* __restrict__ out /* d_out */,
                                                  unsigned int* __restrict__ wsb) {
    const long long total = (long long)NDATA * D_SZ;  // 64,000,000
    const long long NV = total / 4;                   // 16,000,000
    long long t = blockIdx.x * 256LL + threadIdx.x;
    const long long nthr = gridDim.x * 256LL;
    const int lane = threadIdx.x & 63;
    const f32x4* src4 = (const f32x4*)src;
    f32x4* out4 = (f32x4*)out;
    for (long long j = t; j < NV; j += nthr) {
        f32x4 v = src4[j];  // plain cached load
        int w8 = __builtin_amdgcn_cvt_pk_fp8_f32(v.x, v.y, 0, false);
        w8 = __builtin_amdgcn_cvt_pk_fp8_f32(v.z, v.w, w8, true);
        wsb[j] = (unsigned int)w8;  // plain store
        float pw = __shfl_up(v.w, 1, 64);
        if (lane == 0 && j > 0) pw = src[4 * j - 1];  // cache-hit neighbor
        if (j > 0) {
            f32x4 w;
            w.x = pw; w.y = v.x; w.z = v.y; w.w = v.z;
            out4[j] = w;  // plain store — NT measured at only ~1.8 TB/s on gfx950
        } else {
            out[1] = v.x; out[2] = v.y; out[3] = v.z;
            out[total] = src[total - 1];
        }
    }
}

// ---------------- fp8 dot helper: 16 elements vs s-chunk ----------------
__device__ __forceinline__ float dot16_fp8(uint4 h, f32x4 s0, f32x4 s1, f32x4 s2, f32x4 s3) {
    float d = 0.0f;
    f32x2 a, c;
    a = __builtin_amdgcn_cvt_pk_f32_fp8((int)h.x, false);
    c = __builtin_amdgcn_cvt_pk_f32_fp8((int)h.x, true);
    d += a.x * s0.x + a.y * s0.y + c.x * s0.z + c.y * s0.w;
    a = __builtin_amdgcn_cvt_pk_f32_fp8((int)h.y, false);
    c = __builtin_amdgcn_cvt_pk_f32_fp8((int)h.y, true);
    d += a.x * s1.x + a.y * s1.y + c.x * s1.z + c.y * s1.w;
    a = __builtin_amdgcn_cvt_pk_f32_fp8((int)h.z, false);
    c = __builtin_amdgcn_cvt_pk_f32_fp8((int)h.z, true);
    d += a.x * s2.x + a.y * s2.y + c.x * s2.z + c.y * s2.w;
    a = __builtin_amdgcn_cvt_pk_f32_fp8((int)h.w, false);
    c = __builtin_amdgcn_cvt_pk_f32_fp8((int)h.w, true);
    d += a.x * s3.x + a.y * s3.y + c.x * s3.z + c.y * s3.w;
    return d;
}

// ---------------- gather from fp8 shadow: 8 lanes/row, 8 rows in flight ----------------
__global__ __launch_bounds__(256) void kneg_fp8(const unsigned int* __restrict__ wsb,
                                                const int* __restrict__ negidx,
                                                const float* __restrict__ s_n,
                                                float2* __restrict__ partials) {
    const int split = blockIdx.x;  // 0..SPLIT-1
    const int b = blockIdx.y;
    const int tid = threadIdx.x;
    const int oct = tid >> 3;  // 32 octets of 8 lanes
    const int o = tid & 7;
    const f32x4* sn4 = (const f32x4*)(s_n + b * D_SZ + o * 16);
    f32x4 s0 = sn4[0], s1 = sn4[1], s2 = sn4[2], s3 = sn4[3];
    float m = -INFINITY, ssum = 0.0f;
    const int KB = K_SZ / SPLIT;             // 512 rows per block
    const int base = b * K_SZ + split * KB;
    for (int it = 0; it < KB / 256; ++it) {  // 2 iters; octet does 8 rows/iter
        int k = it * 256 + oct * 8;
        int4 ia = *(const int4*)(negidx + base + k);
        int4 ib = *(const int4*)(negidx + base + k + 4);
        uint4 h0 = ((const uint4*)(wsb + (long long)ia.x * 32))[o];
        uint4 h1 = ((const uint4*)(wsb + (long long)ia.y * 32))[o];
        uint4 h2 = ((const uint4*)(wsb + (long long)ia.z * 32))[o];
        uint4 h3 = ((const uint4*)(wsb + (long long)ia.w * 32))[o];
        uint4 h4 = ((const uint4*)(wsb + (long long)ib.x * 32))[o];
        uint4 h5 = ((const uint4*)(wsb + (long long)ib.y * 32))[o];
        uint4 h6 = ((const uint4*)(wsb + (long long)ib.z * 32))[o];
        uint4 h7 = ((const uint4*)(wsb + (long long)ib.w * 32))[o];
        float d0 = dot16_fp8(h0, s0, s1, s2, s3);
        float d1 = dot16_fp8(h1, s0, s1, s2, s3);
        float d2 = dot16_fp8(h2, s0, s1, s2, s3);
        float d3 = dot16_fp8(h3, s0, s1, s2, s3);
        float d4 = dot16_fp8(h4, s0, s1, s2, s3);
        float d5 = dot16_fp8(h5, s0, s1, s2, s3);
        float d6 = dot16_fp8(h6, s0, s1, s2, s3);
        float d7 = dot16_fp8(h7, s0, s1, s2, s3);
        for (int s = 1; s < 8; s <<= 1) {
            d0 += __shfl_xor(d0, s, 64);
            d1 += __shfl_xor(d1, s, 64);
            d2 += __shfl_xor(d2, s, 64);
            d3 += __shfl_xor(d3, s, 64);
            d4 += __shfl_xor(d4, s, 64);
            d5 += __shfl_xor(d5, s, 64);
            d6 += __shfl_xor(d6, s, 64);
            d7 += __shfl_xor(d7, s, 64);
        }
        d0 *= (1.0f / TEMP); d1 *= (1.0f / TEMP); d2 *= (1.0f / TEMP); d3 *= (1.0f / TEMP);
        d4 *= (1.0f / TEMP); d5 *= (1.0f / TEMP); d6 *= (1.0f / TEMP); d7 *= (1.0f / TEMP);
        float mx = fmaxf(fmaxf(fmaxf(d0, d1), fmaxf(d2, d3)),
                         fmaxf(fmaxf(d4, d5), fmaxf(d6, d7)));
        float mn = fmaxf(m, mx);
        ssum = ssum * __expf(m - mn) + __expf(d0 - mn) + __expf(d1 - mn) +
               __expf(d2 - mn) + __expf(d3 - mn) + __expf(d4 - mn) +
               __expf(d5 - mn) + __expf(d6 - mn) + __expf(d7 - mn);
        m = mn;
    }
    __shared__ float2 gp[32];
    if (o == 0) gp[oct] = make_float2(m, ssum);
    __syncthreads();
    if (tid == 0) {
        float M = gp[0].x, S = gp[0].y;
        for (int g = 1; g < 32; ++g) {
            float mg = gp[g].x, sg = gp[g].y;
            float mn = fmaxf(M, mg);
            S = S * __expf(M - mn) + sg * __expf(mg - mn);
            M = mn;
        }
        partials[b * SPLIT + split] = make_float2(M, S);
    }
}

// ---------------- momentum scatter-update (last-wins) ----------------
__global__ void kupdate(const int* __restrict__ indices, const float* __restrict__ bank,
                        const float* __restrict__ t_n, float* __restrict__ outBank /* d_out+1 */) {
    int j = blockIdx.x;
    int l = threadIdx.x;  // 64
    int idx = indices[j];
    for (int j2 = j + 1; j2 < B_SZ; ++j2)
        if (indices[j2] == idx) return;  // last occurrence wins
    float2 bv = ((const float2*)(bank + (long long)idx * D_SZ))[l];
    float2 tv = ((const float2*)(t_n + j * D_SZ))[l];
    float2 u = {MOM * bv.x + (1.0f - MOM) * tv.x, MOM * bv.y + (1.0f - MOM) * tv.y};
    float ss = u.x * u.x + u.y * u.y;
    for (int m = 1; m < 64; m <<= 1) ss += __shfl_xor(ss, m, 64);
    float inv = 1.0f / fmaxf(sqrtf(ss), EPSN);
    float* dst = outBank + (long long)idx * D_SZ + l * 2;
    dst[0] = u.x * inv;
    dst[1] = u.y * inv;
}

// ---------------- combine partials -> loss ----------------
__global__ void kfinal(const float2* __restrict__ partials, const float* __restrict__ pos,
                       float* __restrict__ out) {
    __shared__ float red[B_SZ];
    int t = threadIdx.x;  // 512
    float M = -INFINITY, S = 0.0f;
    for (int p = 0; p < SPLIT; ++p) {
        float2 ms = partials[t * SPLIT + p];
        float mn = fmaxf(M, ms.x);
        S = S * __expf(M - mn) + ms.y * __expf(ms.x - mn);
        M = mn;
    }
    float pl = pos[t];
    float mn = fmaxf(M, pl);
    S = S * __expf(M - mn) + __expf(pl - mn);
    M = mn;
    red[t] = M + logf(S) - pl;
    __syncthreads();
    for (int o = 256; o > 0; o >>= 1) {
        if (t < o) red[t] += red[t + o];
        __syncthreads();
    }
    if (t == 0) out[0] = red[0] * (1.0f / (float)B_SZ);
}

extern "C" void kernel_launch(void* const* d_in, const int* in_sizes, int n_in,
                              void* d_out, int out_size, void* d_ws, size_t ws_size,
                              hipStream_t stream) {
    const float* student = (const float*)d_in[0];
    const float* teacher = (const float*)d_in[1];
    const float* bank    = (const float*)d_in[2];
    const int*   indices = (const int*)d_in[3];
    const int*   negidx  = (const int*)d_in[4];
    float* out = (float*)d_out;

    // workspace: small arrays in first 1 MB, fp8 shadow bank after (61 MB)
    float* s_n      = (float*)d_ws;              // 65536 f
    float* t_n      = s_n + B_SZ * D_SZ;         // 65536 f
    float* pos      = t_n + B_SZ * D_SZ;         // 512 f
    float2* partials = (float2*)(pos + B_SZ);    // 512*SPLIT float2
    unsigned int* wsb = (unsigned int*)((char*)d_ws + WSB_OFF);

    knorm<<<B_SZ, 64, 0, stream>>>(student, teacher, s_n, t_n, pos);
    kcopy_emit<<<4096, 256, 0, stream>>>(bank, out, wsb);
    dim3 g(SPLIT, B_SZ);
    kneg_fp8<<<g, 256, 0, stream>>>(wsb, negidx, s_n, partials);
    kupdate<<<B_SZ, 64, 0, stream>>>(indices, bank, t_n, out + 1);
    kfinal<<<1, B_SZ, 0, stream>>>(partials, pos, out);
}